// Round 1
// baseline (16346.826 us; speedup 1.0000x reference)
//
#include <hip/hip_runtime.h>
#include <math.h>

#define TT      1024
#define BATCH   512
#define UNITSN  256
#define ZDIM    1024   // 4*UNITS
#define NFEAT   32
#define OSTEPS  32
#define NBND    31
#define BT      4      // batch rows per block
#define NTHR    512    // threads per LSTM block
#define OUT_MU  (BATCH*OSTEPS*NFEAT)   // 524288
#define OUT_SG  (OUT_MU + BATCH)

__device__ __forceinline__ float sigm(float x) { return 1.0f / (1.0f + expf(-x)); }

// ---------------- _T_BASE on device (fp64, mirrors the numpy code) -------------
__global__ void k_tbase(float* __restrict__ tb) {
    int i = threadIdx.x;
    if (i >= NBND) return;
    double step = (0.9999 - 0.0001) / 30.0;
    double p = 0.0001 + (double)i * step;
    if (i == 30) p = 0.9999;  // numpy linspace pins the endpoint

    const double a0=-39.69683028665376, a1=220.9460984245205, a2=-275.9285104469687,
                 a3=138.357751867269,   a4=-30.66479806614716, a5=2.506628277459239;
    const double b0=-54.47609879822406, b1=161.5858368580409, b2=-155.6989798598866,
                 b3=66.80131188771972,  b4=-13.28068155288572;
    const double c0=-0.007784894002430293, c1=-0.3223964580411365, c2=-2.400758277161838,
                 c3=-2.549732539343734,    c4=4.374664141464968,   c5=2.938163982698783;
    const double d0=0.007784695709041462,  d1=0.3224671290700398,  d2=2.445134137142996,
                 d3=3.754408661907416;
    const double lo = 0.02425, hi = 1.0 - 0.02425;
    double z;
    if (p < lo) {
        double q = sqrt(-2.0 * log(p));
        z = (((((c0*q+c1)*q+c2)*q+c3)*q+c4)*q+c5) / ((((d0*q+d1)*q+d2)*q+d3)*q+1.0);
    } else if (p <= hi) {
        double q = p - 0.5;
        double r = q*q;
        z = (((((a0*r+a1)*r+a2)*r+a3)*r+a4)*r+a5)*q /
            (((((b0*r+b1)*r+b2)*r+b3)*r+b4)*r+1.0);
    } else {
        double q = sqrt(-2.0 * log(1.0 - p));
        z = -((((((c0*q+c1)*q+c2)*q+c3)*q+c4)*q+c5) / ((((d0*q+d1)*q+d2)*q+d3)*q+1.0));
    }
    double z2=z*z, z3=z2*z, z5=z3*z2, z7=z5*z2, z9=z7*z2;
    double g1=(z3+z)/4.0;
    double g2=(5.0*z5+16.0*z3+3.0*z)/96.0;
    double g3=(3.0*z7+19.0*z5+17.0*z3-15.0*z)/384.0;
    double g4=(79.0*z9+776.0*z7+1482.0*z5-1920.0*z3-945.0*z)/92160.0;
    const double df = 15.0;
    double t = z + g1/df + g2/(df*df) + g3/(df*df*df) + g4/(df*df*df*df);
    tb[i] = (float)t;
}

// ---------------- per-row mean / std ----------------
__global__ __launch_bounds__(1024)
void k_musig(const float* __restrict__ x, float* __restrict__ out,
             float* __restrict__ muv, float* __restrict__ sgv) {
    int b = blockIdx.x;
    int t = threadIdx.x;
    __shared__ float red[16];
    __shared__ float sMu;
    float v = x[(size_t)b * TT + t];

    float s = v;
    #pragma unroll
    for (int o = 32; o >= 1; o >>= 1) s += __shfl_xor(s, o, 64);
    int wid = t >> 6, lane = t & 63;
    if (lane == 0) red[wid] = s;
    __syncthreads();
    if (t == 0) {
        float tot = 0.f;
        for (int w = 0; w < 16; ++w) tot += red[w];
        sMu = tot * (1.0f / 1024.0f);
    }
    __syncthreads();
    float mu = sMu;
    float d = v - mu;
    s = d * d;
    #pragma unroll
    for (int o = 32; o >= 1; o >>= 1) s += __shfl_xor(s, o, 64);
    if (lane == 0) red[wid] = s;
    __syncthreads();
    if (t == 0) {
        float tot = 0.f;
        for (int w = 0; w < 16; ++w) tot += red[w];
        float sg = sqrtf(tot * (1.0f / 1024.0f));
        out[OUT_MU + b] = mu;
        out[OUT_SG + b] = sg;
        muv[b] = mu;
        sgv[b] = sg;
    }
}

// ---------------- fused binning + LSTM encoder + decoder ----------------
__global__ __launch_bounds__(NTHR)
void k_lstm(const float* __restrict__ x,     // (B,T)
            const float* __restrict__ Kmat,  // (32,1024)
            const float* __restrict__ Rec,   // (256,1024)
            const float* __restrict__ Bias,  // (1024)
            const float* __restrict__ Dw,    // (256,32)
            const float* __restrict__ Db,    // (32)
            const float* __restrict__ tb,    // (31)
            const float* __restrict__ muv,
            const float* __restrict__ sgv,
            float* __restrict__ out)         // preds at offset 0
{
    __shared__ float sHT[UNITSN][BT];          // h transposed: sHT[u][r]
    __shared__ float sZ[BT][ZDIM];
    __shared__ float sBias[ZDIM];
    __shared__ unsigned char sIdx[BT][TT];
    __shared__ float sBnd[BT][NBND];
    __shared__ float sPT[NFEAT][BT];           // p transposed: sPT[f][r]
    __shared__ float sLog[BT][NFEAT];

    const int tid = threadIdx.x;
    const int b0  = blockIdx.x * BT;

    // stage bias
    sBias[tid]        = Bias[tid];
    sBias[tid + NTHR] = Bias[tid + NTHR];

    // per-row bin bounds
    if (tid < BT * 32) {
        int r = tid >> 5, j = tid & 31;
        if (j < NBND) sBnd[r][j] = tb[j] * sgv[b0 + r] + muv[b0 + r];
    }
    // h0 = 0
    {
        float* ph = &sHT[0][0];
        ph[tid] = 0.f;
        ph[tid + NTHR] = 0.f;
    }
    __syncthreads();

    // searchsorted(side='right') for all BT rows
    for (int e = tid; e < BT * TT; e += NTHR) {
        int r = e >> 10, t = e & 1023;
        float xv = x[(size_t)(b0 + r) * TT + t];
        int id = 0;
        #pragma unroll
        for (int q = 0; q < NBND; ++q) id += (sBnd[r][q] <= xv) ? 1 : 0;
        sIdx[r][t] = (unsigned char)id;
    }
    __syncthreads();

    const int rB  = tid >> 7;          // phase-B row (0..3)
    const int uB  = tid & 127;         // phase-B unit (plus uB+128)
    const int uB2 = uB + 128;
    const int j0  = tid << 1;          // phase-A column pair
    float c0 = 0.f, c1 = 0.f;

    // phase B (gates) as a macro-ish lambda
    auto phaseB = [&]() {
        float zi = sZ[rB][uB], zf = sZ[rB][uB + 256], zg = sZ[rB][uB + 512], zo = sZ[rB][uB + 768];
        c0 = sigm(zf) * c0 + sigm(zi) * tanhf(zg);
        sHT[uB][rB] = sigm(zo) * tanhf(c0);
        zi = sZ[rB][uB2]; zf = sZ[rB][uB2 + 256]; zg = sZ[rB][uB2 + 512]; zo = sZ[rB][uB2 + 768];
        c1 = sigm(zf) * c1 + sigm(zi) * tanhf(zg);
        sHT[uB2][rB] = sigm(zo) * tanhf(c1);
    };

    auto recLoop = [&](float2& a0, float2& a1, float2& a2, float2& a3) {
        #pragma unroll 8
        for (int k = 0; k < UNITSN; ++k) {
            float2 w  = *(const float2*)&Rec[(size_t)k * ZDIM + j0];
            float4 h4 = *(const float4*)&sHT[k][0];
            a0.x = fmaf(h4.x, w.x, a0.x); a0.y = fmaf(h4.x, w.y, a0.y);
            a1.x = fmaf(h4.y, w.x, a1.x); a1.y = fmaf(h4.y, w.y, a1.y);
            a2.x = fmaf(h4.z, w.x, a2.x); a2.y = fmaf(h4.z, w.y, a2.y);
            a3.x = fmaf(h4.w, w.x, a3.x); a3.y = fmaf(h4.w, w.y, a3.y);
        }
    };

    auto softmaxStore = [&](int s) {
        if (tid < BT * NFEAT) {
            int r = tid >> 5, f = tid & 31;
            float acc = Db[f];
            #pragma unroll 4
            for (int u = 0; u < UNITSN; ++u) acc = fmaf(sHT[u][r], Dw[u * NFEAT + f], acc);
            sLog[r][f] = acc;
        }
        __syncthreads();
        if (tid < BT) {
            int r = tid;
            float m = sLog[r][0];
            for (int f = 1; f < NFEAT; ++f) m = fmaxf(m, sLog[r][f]);
            float ssum = 0.f;
            for (int f = 0; f < NFEAT; ++f) {
                float e = expf(sLog[r][f] - m);
                sLog[r][f] = e;
                ssum += e;
            }
            float inv = 1.0f / ssum;
            for (int f = 0; f < NFEAT; ++f) {
                float p = sLog[r][f] * inv;
                sPT[f][r] = p;
                out[((size_t)(b0 + r) * OSTEPS + s) * NFEAT + f] = p;
            }
        }
        __syncthreads();
    };

    // ---------------- encoder: 1024 steps ----------------
    for (int t = 0; t < TT; ++t) {
        float2 bj = *(const float2*)&sBias[j0];
        int i0 = sIdx[0][t], i1 = sIdx[1][t], i2 = sIdx[2][t], i3 = sIdx[3][t];
        float2 k0 = *(const float2*)&Kmat[(size_t)i0 * ZDIM + j0];
        float2 k1 = *(const float2*)&Kmat[(size_t)i1 * ZDIM + j0];
        float2 k2 = *(const float2*)&Kmat[(size_t)i2 * ZDIM + j0];
        float2 k3 = *(const float2*)&Kmat[(size_t)i3 * ZDIM + j0];
        float2 a0 = make_float2(bj.x + k0.x, bj.y + k0.y);
        float2 a1 = make_float2(bj.x + k1.x, bj.y + k1.y);
        float2 a2 = make_float2(bj.x + k2.x, bj.y + k2.y);
        float2 a3 = make_float2(bj.x + k3.x, bj.y + k3.y);
        recLoop(a0, a1, a2, a3);
        *(float2*)&sZ[0][j0] = a0;
        *(float2*)&sZ[1][j0] = a1;
        *(float2*)&sZ[2][j0] = a2;
        *(float2*)&sZ[3][j0] = a3;
        __syncthreads();
        phaseB();
        __syncthreads();
    }

    // first prediction (step 0)
    softmaxStore(0);

    // ---------------- decoder: 31 steps ----------------
    for (int s = 1; s < OSTEPS; ++s) {
        float2 bj = *(const float2*)&sBias[j0];
        float2 a0 = make_float2(bj.x, bj.y);
        float2 a1 = a0, a2 = a0, a3 = a0;
        #pragma unroll 8
        for (int i = 0; i < NFEAT; ++i) {
            float2 w  = *(const float2*)&Kmat[(size_t)i * ZDIM + j0];
            float4 p4 = *(const float4*)&sPT[i][0];
            a0.x = fmaf(p4.x, w.x, a0.x); a0.y = fmaf(p4.x, w.y, a0.y);
            a1.x = fmaf(p4.y, w.x, a1.x); a1.y = fmaf(p4.y, w.y, a1.y);
            a2.x = fmaf(p4.z, w.x, a2.x); a2.y = fmaf(p4.z, w.y, a2.y);
            a3.x = fmaf(p4.w, w.x, a3.x); a3.y = fmaf(p4.w, w.y, a3.y);
        }
        recLoop(a0, a1, a2, a3);
        *(float2*)&sZ[0][j0] = a0;
        *(float2*)&sZ[1][j0] = a1;
        *(float2*)&sZ[2][j0] = a2;
        *(float2*)&sZ[3][j0] = a3;
        __syncthreads();
        phaseB();
        __syncthreads();
        softmaxStore(s);
    }
}

extern "C" void kernel_launch(void* const* d_in, const int* in_sizes, int n_in,
                              void* d_out, int out_size, void* d_ws, size_t ws_size,
                              hipStream_t stream) {
    const float* inputs = (const float*)d_in[0];
    const float* kernel = (const float*)d_in[1];
    const float* rec    = (const float*)d_in[2];
    const float* bias   = (const float*)d_in[3];
    const float* dw     = (const float*)d_in[4];
    const float* db     = (const float*)d_in[5];
    float* out = (float*)d_out;

    float* tb  = (float*)d_ws;       // 31 floats (padded to 64)
    float* muv = tb + 64;            // 512
    float* sgv = muv + BATCH;        // 512

    k_tbase<<<1, 32, 0, stream>>>(tb);
    k_musig<<<BATCH, 1024, 0, stream>>>(inputs, out, muv, sgv);
    k_lstm<<<BATCH / BT, NTHR, 0, stream>>>(inputs, kernel, rec, bias, dw, db,
                                            tb, muv, sgv, out);
}

// Round 2
// 8357.837 us; speedup vs baseline: 1.9559x; 1.9559x over previous
//
#include <hip/hip_runtime.h>
#include <math.h>

#define TT      1024
#define BATCH   512
#define UNITSN  256
#define ZDIM    1024   // 4*UNITS
#define NFEAT   32
#define OSTEPS  32
#define NBND    31
#define OUT_MU  (BATCH*OSTEPS*NFEAT)   // 524288
#define OUT_SG  (OUT_MU + BATCH)

typedef _Float16 v2h __attribute__((ext_vector_type(2)));
union UH2 { unsigned int u; v2h h; };
__device__ __forceinline__ v2h as_v2h(unsigned int u) { UH2 c; c.u = u; return c.h; }
__device__ __forceinline__ unsigned short f2h(float f) {
    union { _Float16 h; unsigned short s; } c; c.h = (_Float16)f; return c.s;
}
__device__ __forceinline__ float sigm(float x)  { return 1.0f / (1.0f + __expf(-x)); }
__device__ __forceinline__ float ftanh(float x) { float e = __expf(2.0f * x); return 1.0f - 2.0f / (e + 1.0f); }

// ---------------- _T_BASE on device (fp64, mirrors the numpy code) -------------
__global__ void k_tbase(float* __restrict__ tb) {
    int i = threadIdx.x;
    if (i >= NBND) return;
    double step = (0.9999 - 0.0001) / 30.0;
    double p = 0.0001 + (double)i * step;
    if (i == 30) p = 0.9999;

    const double a0=-39.69683028665376, a1=220.9460984245205, a2=-275.9285104469687,
                 a3=138.357751867269,   a4=-30.66479806614716, a5=2.506628277459239;
    const double b0=-54.47609879822406, b1=161.5858368580409, b2=-155.6989798598866,
                 b3=66.80131188771972,  b4=-13.28068155288572;
    const double c0=-0.007784894002430293, c1=-0.3223964580411365, c2=-2.400758277161838,
                 c3=-2.549732539343734,    c4=4.374664141464968,   c5=2.938163982698783;
    const double d0=0.007784695709041462,  d1=0.3224671290700398,  d2=2.445134137142996,
                 d3=3.754408661907416;
    const double lo = 0.02425, hi = 1.0 - 0.02425;
    double z;
    if (p < lo) {
        double q = sqrt(-2.0 * log(p));
        z = (((((c0*q+c1)*q+c2)*q+c3)*q+c4)*q+c5) / ((((d0*q+d1)*q+d2)*q+d3)*q+1.0);
    } else if (p <= hi) {
        double q = p - 0.5;
        double r = q*q;
        z = (((((a0*r+a1)*r+a2)*r+a3)*r+a4)*r+a5)*q /
            (((((b0*r+b1)*r+b2)*r+b3)*r+b4)*r+1.0);
    } else {
        double q = sqrt(-2.0 * log(1.0 - p));
        z = -((((((c0*q+c1)*q+c2)*q+c3)*q+c4)*q+c5) / ((((d0*q+d1)*q+d2)*q+d3)*q+1.0));
    }
    double z2=z*z, z3=z2*z, z5=z3*z2, z7=z5*z2, z9=z7*z2;
    double g1=(z3+z)/4.0;
    double g2=(5.0*z5+16.0*z3+3.0*z)/96.0;
    double g3=(3.0*z7+19.0*z5+17.0*z3-15.0*z)/384.0;
    double g4=(79.0*z9+776.0*z7+1482.0*z5-1920.0*z3-945.0*z)/92160.0;
    const double df = 15.0;
    double t = z + g1/df + g2/(df*df) + g3/(df*df*df) + g4/(df*df*df*df);
    tb[i] = (float)t;
}

// ---------------- per-row mean / std ----------------
__global__ __launch_bounds__(1024)
void k_musig(const float* __restrict__ x, float* __restrict__ out,
             float* __restrict__ muv, float* __restrict__ sgv) {
    int b = blockIdx.x;
    int t = threadIdx.x;
    __shared__ float red[16];
    __shared__ float sMu;
    float v = x[(size_t)b * TT + t];

    float s = v;
    #pragma unroll
    for (int o = 32; o >= 1; o >>= 1) s += __shfl_xor(s, o, 64);
    int wid = t >> 6, lane = t & 63;
    if (lane == 0) red[wid] = s;
    __syncthreads();
    if (t == 0) {
        float tot = 0.f;
        for (int w = 0; w < 16; ++w) tot += red[w];
        sMu = tot * (1.0f / 1024.0f);
    }
    __syncthreads();
    float mu = sMu;
    float d = v - mu;
    s = d * d;
    #pragma unroll
    for (int o = 32; o >= 1; o >>= 1) s += __shfl_xor(s, o, 64);
    if (lane == 0) red[wid] = s;
    __syncthreads();
    if (t == 0) {
        float tot = 0.f;
        for (int w = 0; w < 16; ++w) tot += red[w];
        float sg = sqrtf(tot * (1.0f / 1024.0f));
        out[OUT_MU + b] = mu;
        out[OUT_SG + b] = sg;
        muv[b] = mu;
        sgv[b] = sg;
    }
}

// ---------------- weight repack: f16-pair, gate-interleaved ----------------
// RecPG[k2*1024 + u*4 + g] = pack_f16( Rec[2k2][g*256+u], Rec[2k2+1][g*256+u] )
__global__ __launch_bounds__(256)
void k_packR(const float* __restrict__ Rec, unsigned int* __restrict__ RecPG) {
    int e = blockIdx.x * 256 + threadIdx.x;   // 0..131071
    int k2 = e >> 10, c = e & 1023;
    int u = c >> 2, g = c & 3;
    int j = g * 256 + u;
    float a = Rec[(size_t)(2 * k2)     * ZDIM + j];
    float b = Rec[(size_t)(2 * k2 + 1) * ZDIM + j];
    UH2 cv; cv.h = v2h{(_Float16)a, (_Float16)b};
    RecPG[e] = cv.u;
}
// KB[i*1024 + u*4 + g] = Kmat[i][g*256+u] + Bias[g*256+u]   (bias folded: rows sum to 1)
__global__ __launch_bounds__(256)
void k_packK(const float* __restrict__ Kmat, const float* __restrict__ Bias,
             float* __restrict__ KB) {
    int e = blockIdx.x * 256 + threadIdx.x;   // 0..32767
    int i = e >> 10, c = e & 1023;
    int u = c >> 2, g = c & 3;
    int j = g * 256 + u;
    KB[e] = Kmat[(size_t)i * ZDIM + j] + Bias[j];
}

// ---------------- fused binning + LSTM encoder + decoder (f16 dot2) ----------------
#define BT2 2
#define NT2 512

__global__ __launch_bounds__(NT2)
void k_lstm2(const float* __restrict__ x,        // (B,T)
             const unsigned int* __restrict__ RecPG, // [128][256][4] packed f16 pairs
             const float* __restrict__ KB,       // [32][256][4] kernel+bias, gate-interleaved
             const float* __restrict__ Dw,       // (256,32)
             const float* __restrict__ Db,       // (32)
             const float* __restrict__ tb,       // (31)
             const float* __restrict__ muv,
             const float* __restrict__ sgv,
             float* __restrict__ out)
{
    __shared__ unsigned int sH2[2][UNITSN];     // double-buffered packed f16 h: [buf][k2*BT2+r]
    __shared__ float sHT[UNITSN][BT2];          // fp32 h for the dense head
    __shared__ unsigned char sIdx[BT2][TT];
    __shared__ float sBnd[BT2][32];
    __shared__ float sPT[NFEAT][BT2];
    __shared__ float sLog[BT2][NFEAT];

    const int tid = threadIdx.x;
    const int b0  = blockIdx.x * BT2;

    if (tid < BT2 * 32) {
        int rr = tid >> 5, j = tid & 31;
        if (j < NBND) sBnd[rr][j] = tb[j] * sgv[b0 + rr] + muv[b0 + rr];
    }
    if (tid < 2 * UNITSN) ((unsigned int*)sH2)[tid] = 0u;
    if (tid < UNITSN * BT2) ((float*)sHT)[tid] = 0.f;
    __syncthreads();

    // searchsorted(side='right')
    for (int e = tid; e < BT2 * TT; e += NT2) {
        int rr = e >> 10, t = e & 1023;
        float xv = x[(size_t)(b0 + rr) * TT + t];
        int id = 0;
        #pragma unroll
        for (int q = 0; q < NBND; ++q) id += (sBnd[rr][q] <= xv) ? 1 : 0;
        sIdx[rr][t] = (unsigned char)id;
    }
    __syncthreads();

    const int r = tid >> 8;                 // row 0..1
    const int u = tid & 255;                // unit
    const int wslot = ((u >> 1) * BT2 + r) * 2 + (u & 1);  // ushort slot in sH2[buf]
    const unsigned int* wp = RecPG + (u << 2);
    float cC = 0.f;
    int cur = 0;

    auto stepBody = [&](float4 a) {
        const unsigned int* hp = &sH2[cur][0];
        #pragma unroll 8
        for (int k2 = 0; k2 < 128; ++k2) {
            uint4 w = *(const uint4*)(wp + (k2 << 10));
            v2h h2 = as_v2h(hp[k2 * BT2 + r]);
            a.x = __builtin_amdgcn_fdot2(h2, as_v2h(w.x), a.x, false);
            a.y = __builtin_amdgcn_fdot2(h2, as_v2h(w.y), a.y, false);
            a.z = __builtin_amdgcn_fdot2(h2, as_v2h(w.z), a.z, false);
            a.w = __builtin_amdgcn_fdot2(h2, as_v2h(w.w), a.w, false);
        }
        // gates in-register: a = (i, f, g, o)
        cC = sigm(a.y) * cC + sigm(a.x) * ftanh(a.z);
        float h = sigm(a.w) * ftanh(cC);
        sHT[u][r] = h;
        ((unsigned short*)&sH2[cur ^ 1][0])[wslot] = f2h(h);
        cur ^= 1;
        __syncthreads();
    };

    auto softmaxStore = [&](int s) {
        if (tid < BT2 * NFEAT) {
            int rr = tid >> 5, f = tid & 31;
            float acc = Db[f];
            #pragma unroll 4
            for (int uu = 0; uu < UNITSN; ++uu) acc = fmaf(sHT[uu][rr], Dw[uu * NFEAT + f], acc);
            sLog[rr][f] = acc;
        }
        __syncthreads();
        if (tid < BT2) {
            int rr = tid;
            float m = sLog[rr][0];
            for (int f = 1; f < NFEAT; ++f) m = fmaxf(m, sLog[rr][f]);
            float ssum = 0.f;
            for (int f = 0; f < NFEAT; ++f) {
                float e = __expf(sLog[rr][f] - m);
                sLog[rr][f] = e;
                ssum += e;
            }
            float inv = 1.0f / ssum;
            for (int f = 0; f < NFEAT; ++f) {
                float p = sLog[rr][f] * inv;
                sPT[f][rr] = p;
                out[((size_t)(b0 + rr) * OSTEPS + s) * NFEAT + f] = p;
            }
        }
        __syncthreads();
    };

    // ---------------- encoder: 1024 steps ----------------
    for (int t = 0; t < TT; ++t) {
        int i0 = sIdx[r][t];
        float4 a = *(const float4*)&KB[(i0 << 10) + (u << 2)];
        stepBody(a);
    }
    softmaxStore(0);

    // ---------------- decoder: 31 steps ----------------
    for (int s = 1; s < OSTEPS; ++s) {
        float4 acc = make_float4(0.f, 0.f, 0.f, 0.f);
        #pragma unroll 8
        for (int i = 0; i < NFEAT; ++i) {
            float4 w = *(const float4*)&KB[(i << 10) + (u << 2)];
            float p = sPT[i][r];
            acc.x = fmaf(p, w.x, acc.x); acc.y = fmaf(p, w.y, acc.y);
            acc.z = fmaf(p, w.z, acc.z); acc.w = fmaf(p, w.w, acc.w);
        }
        stepBody(acc);
        softmaxStore(s);
    }
}

// ---------------- fallback (round-1 fp32 path) if workspace too small ----------------
#define BT 4
#define NTHR 512
__global__ __launch_bounds__(NTHR)
void k_lstm(const float* __restrict__ x, const float* __restrict__ Kmat,
            const float* __restrict__ Rec, const float* __restrict__ Bias,
            const float* __restrict__ Dw, const float* __restrict__ Db,
            const float* __restrict__ tb, const float* __restrict__ muv,
            const float* __restrict__ sgv, float* __restrict__ out)
{
    __shared__ float sHT[UNITSN][BT];
    __shared__ float sZ[BT][ZDIM];
    __shared__ float sBias[ZDIM];
    __shared__ unsigned char sIdx[BT][TT];
    __shared__ float sBnd[BT][NBND];
    __shared__ float sPT[NFEAT][BT];
    __shared__ float sLog[BT][NFEAT];

    const int tid = threadIdx.x;
    const int b0  = blockIdx.x * BT;
    sBias[tid] = Bias[tid];
    sBias[tid + NTHR] = Bias[tid + NTHR];
    if (tid < BT * 32) {
        int r = tid >> 5, j = tid & 31;
        if (j < NBND) sBnd[r][j] = tb[j] * sgv[b0 + r] + muv[b0 + r];
    }
    { float* ph = &sHT[0][0]; ph[tid] = 0.f; ph[tid + NTHR] = 0.f; }
    __syncthreads();
    for (int e = tid; e < BT * TT; e += NTHR) {
        int r = e >> 10, t = e & 1023;
        float xv = x[(size_t)(b0 + r) * TT + t];
        int id = 0;
        #pragma unroll
        for (int q = 0; q < NBND; ++q) id += (sBnd[r][q] <= xv) ? 1 : 0;
        sIdx[r][t] = (unsigned char)id;
    }
    __syncthreads();
    const int rB = tid >> 7, uB = tid & 127, uB2 = uB + 128, j0 = tid << 1;
    float c0 = 0.f, c1 = 0.f;
    auto phaseB = [&]() {
        float zi = sZ[rB][uB], zf = sZ[rB][uB+256], zg = sZ[rB][uB+512], zo = sZ[rB][uB+768];
        c0 = sigm(zf) * c0 + sigm(zi) * tanhf(zg);
        sHT[uB][rB] = sigm(zo) * tanhf(c0);
        zi = sZ[rB][uB2]; zf = sZ[rB][uB2+256]; zg = sZ[rB][uB2+512]; zo = sZ[rB][uB2+768];
        c1 = sigm(zf) * c1 + sigm(zi) * tanhf(zg);
        sHT[uB2][rB] = sigm(zo) * tanhf(c1);
    };
    auto recLoop = [&](float2& a0, float2& a1, float2& a2, float2& a3) {
        #pragma unroll 8
        for (int k = 0; k < UNITSN; ++k) {
            float2 w  = *(const float2*)&Rec[(size_t)k * ZDIM + j0];
            float4 h4 = *(const float4*)&sHT[k][0];
            a0.x = fmaf(h4.x, w.x, a0.x); a0.y = fmaf(h4.x, w.y, a0.y);
            a1.x = fmaf(h4.y, w.x, a1.x); a1.y = fmaf(h4.y, w.y, a1.y);
            a2.x = fmaf(h4.z, w.x, a2.x); a2.y = fmaf(h4.z, w.y, a2.y);
            a3.x = fmaf(h4.w, w.x, a3.x); a3.y = fmaf(h4.w, w.y, a3.y);
        }
    };
    auto softmaxStore = [&](int s) {
        if (tid < BT * NFEAT) {
            int r = tid >> 5, f = tid & 31;
            float acc = Db[f];
            #pragma unroll 4
            for (int uu = 0; uu < UNITSN; ++uu) acc = fmaf(sHT[uu][r], Dw[uu * NFEAT + f], acc);
            sLog[r][f] = acc;
        }
        __syncthreads();
        if (tid < BT) {
            int r = tid;
            float m = sLog[r][0];
            for (int f = 1; f < NFEAT; ++f) m = fmaxf(m, sLog[r][f]);
            float ssum = 0.f;
            for (int f = 0; f < NFEAT; ++f) { float e = expf(sLog[r][f] - m); sLog[r][f] = e; ssum += e; }
            float inv = 1.0f / ssum;
            for (int f = 0; f < NFEAT; ++f) {
                float p = sLog[r][f] * inv;
                sPT[f][r] = p;
                out[((size_t)(b0 + r) * OSTEPS + s) * NFEAT + f] = p;
            }
        }
        __syncthreads();
    };
    for (int t = 0; t < TT; ++t) {
        float2 bj = *(const float2*)&sBias[j0];
        int i0 = sIdx[0][t], i1 = sIdx[1][t], i2 = sIdx[2][t], i3 = sIdx[3][t];
        float2 k0 = *(const float2*)&Kmat[(size_t)i0 * ZDIM + j0];
        float2 k1 = *(const float2*)&Kmat[(size_t)i1 * ZDIM + j0];
        float2 k2 = *(const float2*)&Kmat[(size_t)i2 * ZDIM + j0];
        float2 k3 = *(const float2*)&Kmat[(size_t)i3 * ZDIM + j0];
        float2 a0 = make_float2(bj.x + k0.x, bj.y + k0.y);
        float2 a1 = make_float2(bj.x + k1.x, bj.y + k1.y);
        float2 a2 = make_float2(bj.x + k2.x, bj.y + k2.y);
        float2 a3 = make_float2(bj.x + k3.x, bj.y + k3.y);
        recLoop(a0, a1, a2, a3);
        *(float2*)&sZ[0][j0] = a0; *(float2*)&sZ[1][j0] = a1;
        *(float2*)&sZ[2][j0] = a2; *(float2*)&sZ[3][j0] = a3;
        __syncthreads();
        phaseB();
        __syncthreads();
    }
    softmaxStore(0);
    for (int s = 1; s < OSTEPS; ++s) {
        float2 bj = *(const float2*)&sBias[j0];
        float2 a0 = make_float2(bj.x, bj.y), a1 = a0, a2 = a0, a3 = a0;
        #pragma unroll 8
        for (int i = 0; i < NFEAT; ++i) {
            float2 w  = *(const float2*)&Kmat[(size_t)i * ZDIM + j0];
            float4 p4 = *(const float4*)&sPT[i][0];
            a0.x = fmaf(p4.x, w.x, a0.x); a0.y = fmaf(p4.x, w.y, a0.y);
            a1.x = fmaf(p4.y, w.x, a1.x); a1.y = fmaf(p4.y, w.y, a1.y);
            a2.x = fmaf(p4.z, w.x, a2.x); a2.y = fmaf(p4.z, w.y, a2.y);
            a3.x = fmaf(p4.w, w.x, a3.x); a3.y = fmaf(p4.w, w.y, a3.y);
        }
        recLoop(a0, a1, a2, a3);
        *(float2*)&sZ[0][j0] = a0; *(float2*)&sZ[1][j0] = a1;
        *(float2*)&sZ[2][j0] = a2; *(float2*)&sZ[3][j0] = a3;
        __syncthreads();
        phaseB();
        __syncthreads();
        softmaxStore(s);
    }
}

extern "C" void kernel_launch(void* const* d_in, const int* in_sizes, int n_in,
                              void* d_out, int out_size, void* d_ws, size_t ws_size,
                              hipStream_t stream) {
    const float* inputs = (const float*)d_in[0];
    const float* kernel = (const float*)d_in[1];
    const float* rec    = (const float*)d_in[2];
    const float* bias   = (const float*)d_in[3];
    const float* dw     = (const float*)d_in[4];
    const float* db     = (const float*)d_in[5];
    float* out = (float*)d_out;

    float* tb  = (float*)d_ws;       // 64 floats
    float* muv = tb + 64;            // 512
    float* sgv = muv + BATCH;        // 512  -> ends at byte 4352

    const size_t recpg_off = 4352;
    const size_t kb_off    = recpg_off + 131072u * 4u;   // 528640
    const size_t need      = kb_off + 32768u * 4u;       // 659712

    k_tbase<<<1, 32, 0, stream>>>(tb);
    k_musig<<<BATCH, 1024, 0, stream>>>(inputs, out, muv, sgv);

    if (ws_size >= need) {
        unsigned int* RecPG = (unsigned int*)((char*)d_ws + recpg_off);
        float*        KB    = (float*)((char*)d_ws + kb_off);
        k_packR<<<512, 256, 0, stream>>>(rec, RecPG);
        k_packK<<<128, 256, 0, stream>>>(kernel, bias, KB);
        k_lstm2<<<BATCH / BT2, NT2, 0, stream>>>(inputs, RecPG, KB, dw, db,
                                                 tb, muv, sgv, out);
    } else {
        k_lstm<<<BATCH / BT, NTHR, 0, stream>>>(inputs, kernel, rec, bias, dw, db,
                                                tb, muv, sgv, out);
    }
}

// Round 3
// 3625.189 us; speedup vs baseline: 4.5092x; 2.3055x over previous
//
#include <hip/hip_runtime.h>
#include <math.h>

#define TT      1024
#define BATCH   512
#define UNITSN  256
#define ZDIM    1024   // 4*UNITS
#define NFEAT   32
#define OSTEPS  32
#define NBND    31
#define OUT_MU  (BATCH*OSTEPS*NFEAT)   // 524288
#define OUT_SG  (OUT_MU + BATCH)

#define NREG    48     // k-pair slots held in VGPRs per thread
#define NLDS    16     // k-pair slots held in LDS per thread (48+16 = 64 = half of 128)

typedef _Float16 v2h __attribute__((ext_vector_type(2)));
union UH2 { unsigned int u; v2h h; };
__device__ __forceinline__ v2h as_v2h(unsigned int u) { UH2 c; c.u = u; return c.h; }
__device__ __forceinline__ unsigned short f2h(float f) {
    union { _Float16 h; unsigned short s; } c; c.h = (_Float16)f; return c.s;
}
__device__ __forceinline__ float sigm(float x)  { return 1.0f / (1.0f + __expf(-x)); }
__device__ __forceinline__ float ftanh(float x) { float e = __expf(2.0f * x); return 1.0f - 2.0f / (e + 1.0f); }

// ---------------- _T_BASE on device (fp64, mirrors the numpy code) -------------
__global__ void k_tbase(float* __restrict__ tb) {
    int i = threadIdx.x;
    if (i >= NBND) return;
    double step = (0.9999 - 0.0001) / 30.0;
    double p = 0.0001 + (double)i * step;
    if (i == 30) p = 0.9999;

    const double a0=-39.69683028665376, a1=220.9460984245205, a2=-275.9285104469687,
                 a3=138.357751867269,   a4=-30.66479806614716, a5=2.506628277459239;
    const double b0=-54.47609879822406, b1=161.5858368580409, b2=-155.6989798598866,
                 b3=66.80131188771972,  b4=-13.28068155288572;
    const double c0=-0.007784894002430293, c1=-0.3223964580411365, c2=-2.400758277161838,
                 c3=-2.549732539343734,    c4=4.374664141464968,   c5=2.938163982698783;
    const double d0=0.007784695709041462,  d1=0.3224671290700398,  d2=2.445134137142996,
                 d3=3.754408661907416;
    const double lo = 0.02425, hi = 1.0 - 0.02425;
    double z;
    if (p < lo) {
        double q = sqrt(-2.0 * log(p));
        z = (((((c0*q+c1)*q+c2)*q+c3)*q+c4)*q+c5) / ((((d0*q+d1)*q+d2)*q+d3)*q+1.0);
    } else if (p <= hi) {
        double q = p - 0.5;
        double r = q*q;
        z = (((((a0*r+a1)*r+a2)*r+a3)*r+a4)*r+a5)*q /
            (((((b0*r+b1)*r+b2)*r+b3)*r+b4)*r+1.0);
    } else {
        double q = sqrt(-2.0 * log(1.0 - p));
        z = -((((((c0*q+c1)*q+c2)*q+c3)*q+c4)*q+c5) / ((((d0*q+d1)*q+d2)*q+d3)*q+1.0));
    }
    double z2=z*z, z3=z2*z, z5=z3*z2, z7=z5*z2, z9=z7*z2;
    double g1=(z3+z)/4.0;
    double g2=(5.0*z5+16.0*z3+3.0*z)/96.0;
    double g3=(3.0*z7+19.0*z5+17.0*z3-15.0*z)/384.0;
    double g4=(79.0*z9+776.0*z7+1482.0*z5-1920.0*z3-945.0*z)/92160.0;
    const double df = 15.0;
    double t = z + g1/df + g2/(df*df) + g3/(df*df*df) + g4/(df*df*df*df);
    tb[i] = (float)t;
}

// ---------------- per-row mean / std ----------------
__global__ __launch_bounds__(1024)
void k_musig(const float* __restrict__ x, float* __restrict__ out,
             float* __restrict__ muv, float* __restrict__ sgv) {
    int b = blockIdx.x;
    int t = threadIdx.x;
    __shared__ float red[16];
    __shared__ float sMu;
    float v = x[(size_t)b * TT + t];

    float s = v;
    #pragma unroll
    for (int o = 32; o >= 1; o >>= 1) s += __shfl_xor(s, o, 64);
    int wid = t >> 6, lane = t & 63;
    if (lane == 0) red[wid] = s;
    __syncthreads();
    if (t == 0) {
        float tot = 0.f;
        for (int w = 0; w < 16; ++w) tot += red[w];
        sMu = tot * (1.0f / 1024.0f);
    }
    __syncthreads();
    float mu = sMu;
    float d = v - mu;
    s = d * d;
    #pragma unroll
    for (int o = 32; o >= 1; o >>= 1) s += __shfl_xor(s, o, 64);
    if (lane == 0) red[wid] = s;
    __syncthreads();
    if (t == 0) {
        float tot = 0.f;
        for (int w = 0; w < 16; ++w) tot += red[w];
        float sg = sqrtf(tot * (1.0f / 1024.0f));
        out[OUT_MU + b] = mu;
        out[OUT_SG + b] = sg;
        muv[b] = mu;
        sgv[b] = sg;
    }
}

// ---------------- weight repack: f16-pair, gate-interleaved ----------------
// RecPG[k2*1024 + u*4 + g] = pack_f16( Rec[2k2][g*256+u], Rec[2k2+1][g*256+u] )
__global__ __launch_bounds__(256)
void k_packR(const float* __restrict__ Rec, unsigned int* __restrict__ RecPG) {
    int e = blockIdx.x * 256 + threadIdx.x;   // 0..131071
    int k2 = e >> 10, c = e & 1023;
    int u = c >> 2, g = c & 3;
    int j = g * 256 + u;
    float a = Rec[(size_t)(2 * k2)     * ZDIM + j];
    float b = Rec[(size_t)(2 * k2 + 1) * ZDIM + j];
    UH2 cv; cv.h = v2h{(_Float16)a, (_Float16)b};
    RecPG[e] = cv.u;
}
// KB[i*1024 + u*4 + g] = Kmat[i][g*256+u] + Bias[g*256+u]   (bias folded: rows sum to 1)
__global__ __launch_bounds__(256)
void k_packK(const float* __restrict__ Kmat, const float* __restrict__ Bias,
             float* __restrict__ KB) {
    int e = blockIdx.x * 256 + threadIdx.x;   // 0..32767
    int i = e >> 10, c = e & 1023;
    int u = c >> 2, g = c & 3;
    int j = g * 256 + u;
    KB[e] = Kmat[(size_t)i * ZDIM + j] + Bias[j];
}

// ---------------- weight-resident LSTM: 2 rows/block, 256 blocks ----------------
// thread = (u, khalf): u = tid>>1 (unit 0..255), khalf = tid&1 (k-half).
// Weight slice: 64 k-pairs x uint4(4 gates): 48 in VGPRs, 16 in LDS. Zero L2/step.
__global__ __launch_bounds__(512, 2)
void k_lstm3(const float* __restrict__ x,           // (B,T)
             const unsigned int* __restrict__ RecPG,// [128][256][4] packed f16 pairs
             const float* __restrict__ KB,          // [32][256][4] kernel+bias
             const float* __restrict__ Dw,          // (256,32)
             const float* __restrict__ Db,          // (32)
             const float* __restrict__ tb,
             const float* __restrict__ muv,
             const float* __restrict__ sgv,
             float* __restrict__ out)
{
    __shared__ uint4 sWlds[NLDS * 512];        // 128 KiB LDS-resident weight slab
    __shared__ unsigned int sHd[2][UNITSN];    // dbuf packed h: dword = (h[2k2],h[2k2+1]) row r at [k2*2+r]
    __shared__ float sHT[UNITSN][2];           // fp32 h for dense head
    __shared__ unsigned char sIdx[2][TT];
    __shared__ float sBnd[2][32];
    __shared__ float sPT[NFEAT][2];
    __shared__ float sLog[2][NFEAT];

    const int tid   = threadIdx.x;
    const int u     = tid >> 1;
    const int khalf = tid & 1;
    const int b0    = blockIdx.x * 2;

    // ---- one-time staging ----
    if (tid < 64) {
        int rr = tid >> 5, j = tid & 31;
        if (j < NBND) sBnd[rr][j] = tb[j] * sgv[b0 + rr] + muv[b0 + rr];
    }
    if (tid < 2 * UNITSN) ((unsigned int*)sHd)[tid] = 0u;
    if (tid < UNITSN * 2) ((float*)sHT)[tid] = 0.f;

    const unsigned int* wbase = RecPG + ((size_t)(khalf * 64) << 10) + (u << 2);
    uint4 Wreg[NREG];
    #pragma unroll
    for (int jj = 0; jj < NREG; ++jj)
        Wreg[jj] = *(const uint4*)(wbase + ((size_t)jj << 10));
    #pragma unroll
    for (int jj = 0; jj < NLDS; ++jj)
        sWlds[jj * 512 + tid] = *(const uint4*)(wbase + ((size_t)(NREG + jj) << 10));

    for (int e = tid; e < 2 * TT; e += 512) {
        int rr = e >> 10, t = e & 1023;
        float xv = x[(size_t)(b0 + rr) * TT + t];
        int id = 0;
        #pragma unroll
        for (int q = 0; q < NBND; ++q) id += (sBnd[rr][q] <= xv) ? 1 : 0;
        sIdx[rr][t] = (unsigned char)id;
    }
    __syncthreads();

    float cC = 0.f;
    int cur = 0;
    const int hbaseo = khalf << 7;             // dword offset of this thread's k-half (64 k2 * 2)
    const int wslot  = (u >> 1) * 4 + khalf * 2 + (u & 1);   // ushort slot for h write

    // core recurrent dot + gates + h store; 'xa0/xa1' are the input-side partials
    auto stepCore = [&](float4 a0, float4 a1, float4 kbSelf) {
        const unsigned int* hp = &sHd[cur][0];
        #pragma unroll
        for (int jj = 0; jj < NREG; ++jj) {
            uint2 hh = *(const uint2*)(hp + hbaseo + (jj << 1));
            uint4 w  = Wreg[jj];
            v2h h0 = as_v2h(hh.x), h1 = as_v2h(hh.y);
            a0.x = __builtin_amdgcn_fdot2(h0, as_v2h(w.x), a0.x, false);
            a0.y = __builtin_amdgcn_fdot2(h0, as_v2h(w.y), a0.y, false);
            a0.z = __builtin_amdgcn_fdot2(h0, as_v2h(w.z), a0.z, false);
            a0.w = __builtin_amdgcn_fdot2(h0, as_v2h(w.w), a0.w, false);
            a1.x = __builtin_amdgcn_fdot2(h1, as_v2h(w.x), a1.x, false);
            a1.y = __builtin_amdgcn_fdot2(h1, as_v2h(w.y), a1.y, false);
            a1.z = __builtin_amdgcn_fdot2(h1, as_v2h(w.z), a1.z, false);
            a1.w = __builtin_amdgcn_fdot2(h1, as_v2h(w.w), a1.w, false);
        }
        #pragma unroll
        for (int jj = 0; jj < NLDS; ++jj) {
            uint2 hh = *(const uint2*)(hp + hbaseo + ((NREG + jj) << 1));
            uint4 w  = sWlds[jj * 512 + tid];
            v2h h0 = as_v2h(hh.x), h1 = as_v2h(hh.y);
            a0.x = __builtin_amdgcn_fdot2(h0, as_v2h(w.x), a0.x, false);
            a0.y = __builtin_amdgcn_fdot2(h0, as_v2h(w.y), a0.y, false);
            a0.z = __builtin_amdgcn_fdot2(h0, as_v2h(w.z), a0.z, false);
            a0.w = __builtin_amdgcn_fdot2(h0, as_v2h(w.w), a0.w, false);
            a1.x = __builtin_amdgcn_fdot2(h1, as_v2h(w.x), a1.x, false);
            a1.y = __builtin_amdgcn_fdot2(h1, as_v2h(w.y), a1.y, false);
            a1.z = __builtin_amdgcn_fdot2(h1, as_v2h(w.z), a1.z, false);
            a1.w = __builtin_amdgcn_fdot2(h1, as_v2h(w.w), a1.w, false);
        }
        // combine k-halves with adjacent lane (tid^1)
        a0.x += __shfl_xor(a0.x, 1); a0.y += __shfl_xor(a0.y, 1);
        a0.z += __shfl_xor(a0.z, 1); a0.w += __shfl_xor(a0.w, 1);
        a1.x += __shfl_xor(a1.x, 1); a1.y += __shfl_xor(a1.y, 1);
        a1.z += __shfl_xor(a1.z, 1); a1.w += __shfl_xor(a1.w, 1);
        // this thread owns row = khalf
        float zi = (khalf == 0) ? a0.x : a1.x;
        float zf = (khalf == 0) ? a0.y : a1.y;
        float zg = (khalf == 0) ? a0.z : a1.z;
        float zo = (khalf == 0) ? a0.w : a1.w;
        zi += kbSelf.x; zf += kbSelf.y; zg += kbSelf.z; zo += kbSelf.w;
        cC = sigm(zf) * cC + sigm(zi) * ftanh(zg);
        float hv = sigm(zo) * ftanh(cC);
        sHT[u][khalf] = hv;
        ((unsigned short*)&sHd[cur ^ 1][0])[wslot] = f2h(hv);
        cur ^= 1;
        __syncthreads();
    };

    auto softmaxStore = [&](int s) {
        if (tid < 64) {
            int rr = tid >> 5, f = tid & 31;
            float acc = Db[f];
            #pragma unroll 4
            for (int uu = 0; uu < UNITSN; ++uu) acc = fmaf(sHT[uu][rr], Dw[uu * NFEAT + f], acc);
            sLog[rr][f] = acc;
        }
        __syncthreads();
        if (tid < 2) {
            int rr = tid;
            float m = sLog[rr][0];
            for (int f = 1; f < NFEAT; ++f) m = fmaxf(m, sLog[rr][f]);
            float ssum = 0.f;
            for (int f = 0; f < NFEAT; ++f) {
                float e = __expf(sLog[rr][f] - m);
                sLog[rr][f] = e;
                ssum += e;
            }
            float inv = 1.0f / ssum;
            for (int f = 0; f < NFEAT; ++f) {
                float p = sLog[rr][f] * inv;
                sPT[f][rr] = p;
                out[((size_t)(b0 + rr) * OSTEPS + s) * NFEAT + f] = p;
            }
        }
        __syncthreads();
    };

    // ---------------- encoder: 1024 steps ----------------
    #pragma unroll 1
    for (int t = 0; t < TT; ++t) {
        int myidx = sIdx[khalf][t];
        float4 kb = *(const float4*)&KB[(myidx << 10) + (u << 2)];  // own row's input term
        stepCore(make_float4(0.f,0.f,0.f,0.f), make_float4(0.f,0.f,0.f,0.f), kb);
    }
    softmaxStore(0);

    // ---------------- decoder: 31 steps ----------------
    #pragma unroll 1
    for (int s = 1; s < OSTEPS; ++s) {
        float4 a0 = make_float4(0.f,0.f,0.f,0.f), a1 = a0;
        // input GEMM, i-range split across khalf (merged by the same shfl combine)
        #pragma unroll
        for (int ii = 0; ii < 16; ++ii) {
            int i = khalf * 16 + ii;
            float4 w = *(const float4*)&KB[(i << 10) + (u << 2)];
            float p0 = sPT[i][0], p1 = sPT[i][1];
            a0.x = fmaf(p0, w.x, a0.x); a0.y = fmaf(p0, w.y, a0.y);
            a0.z = fmaf(p0, w.z, a0.z); a0.w = fmaf(p0, w.w, a0.w);
            a1.x = fmaf(p1, w.x, a1.x); a1.y = fmaf(p1, w.y, a1.y);
            a1.z = fmaf(p1, w.z, a1.z); a1.w = fmaf(p1, w.w, a1.w);
        }
        stepCore(a0, a1, make_float4(0.f,0.f,0.f,0.f));
        softmaxStore(s);
    }
}

// ---------------- fallback (round-1 fp32 path) if workspace too small ----------------
#define BT 4
#define NTHR 512
__global__ __launch_bounds__(NTHR)
void k_lstm(const float* __restrict__ x, const float* __restrict__ Kmat,
            const float* __restrict__ Rec, const float* __restrict__ Bias,
            const float* __restrict__ Dw, const float* __restrict__ Db,
            const float* __restrict__ tb, const float* __restrict__ muv,
            const float* __restrict__ sgv, float* __restrict__ out)
{
    __shared__ float sHT[UNITSN][BT];
    __shared__ float sZ[BT][ZDIM];
    __shared__ float sBias[ZDIM];
    __shared__ unsigned char sIdx[BT][TT];
    __shared__ float sBnd[BT][NBND];
    __shared__ float sPT[NFEAT][BT];
    __shared__ float sLog[BT][NFEAT];

    const int tid = threadIdx.x;
    const int b0  = blockIdx.x * BT;
    sBias[tid] = Bias[tid];
    sBias[tid + NTHR] = Bias[tid + NTHR];
    if (tid < BT * 32) {
        int r = tid >> 5, j = tid & 31;
        if (j < NBND) sBnd[r][j] = tb[j] * sgv[b0 + r] + muv[b0 + r];
    }
    { float* ph = &sHT[0][0]; ph[tid] = 0.f; ph[tid + NTHR] = 0.f; }
    __syncthreads();
    for (int e = tid; e < BT * TT; e += NTHR) {
        int r = e >> 10, t = e & 1023;
        float xv = x[(size_t)(b0 + r) * TT + t];
        int id = 0;
        #pragma unroll
        for (int q = 0; q < NBND; ++q) id += (sBnd[r][q] <= xv) ? 1 : 0;
        sIdx[r][t] = (unsigned char)id;
    }
    __syncthreads();
    const int rB = tid >> 7, uB = tid & 127, uB2 = uB + 128, j0 = tid << 1;
    float c0 = 0.f, c1 = 0.f;
    auto phaseB = [&]() {
        float zi = sZ[rB][uB], zf = sZ[rB][uB+256], zg = sZ[rB][uB+512], zo = sZ[rB][uB+768];
        c0 = sigm(zf) * c0 + sigm(zi) * tanhf(zg);
        sHT[uB][rB] = sigm(zo) * tanhf(c0);
        zi = sZ[rB][uB2]; zf = sZ[rB][uB2+256]; zg = sZ[rB][uB2+512]; zo = sZ[rB][uB2+768];
        c1 = sigm(zf) * c1 + sigm(zi) * tanhf(zg);
        sHT[uB2][rB] = sigm(zo) * tanhf(c1);
    };
    auto recLoop = [&](float2& a0, float2& a1, float2& a2, float2& a3) {
        #pragma unroll 8
        for (int k = 0; k < UNITSN; ++k) {
            float2 w  = *(const float2*)&Rec[(size_t)k * ZDIM + j0];
            float4 h4 = *(const float4*)&sHT[k][0];
            a0.x = fmaf(h4.x, w.x, a0.x); a0.y = fmaf(h4.x, w.y, a0.y);
            a1.x = fmaf(h4.y, w.x, a1.x); a1.y = fmaf(h4.y, w.y, a1.y);
            a2.x = fmaf(h4.z, w.x, a2.x); a2.y = fmaf(h4.z, w.y, a2.y);
            a3.x = fmaf(h4.w, w.x, a3.x); a3.y = fmaf(h4.w, w.y, a3.y);
        }
    };
    auto softmaxStore = [&](int s) {
        if (tid < BT * NFEAT) {
            int r = tid >> 5, f = tid & 31;
            float acc = Db[f];
            #pragma unroll 4
            for (int uu = 0; uu < UNITSN; ++uu) acc = fmaf(sHT[uu][r], Dw[uu * NFEAT + f], acc);
            sLog[r][f] = acc;
        }
        __syncthreads();
        if (tid < BT) {
            int r = tid;
            float m = sLog[r][0];
            for (int f = 1; f < NFEAT; ++f) m = fmaxf(m, sLog[r][f]);
            float ssum = 0.f;
            for (int f = 0; f < NFEAT; ++f) { float e = expf(sLog[r][f] - m); sLog[r][f] = e; ssum += e; }
            float inv = 1.0f / ssum;
            for (int f = 0; f < NFEAT; ++f) {
                float p = sLog[r][f] * inv;
                sPT[f][r] = p;
                out[((size_t)(b0 + r) * OSTEPS + s) * NFEAT + f] = p;
            }
        }
        __syncthreads();
    };
    for (int t = 0; t < TT; ++t) {
        float2 bj = *(const float2*)&sBias[j0];
        int i0 = sIdx[0][t], i1 = sIdx[1][t], i2 = sIdx[2][t], i3 = sIdx[3][t];
        float2 k0 = *(const float2*)&Kmat[(size_t)i0 * ZDIM + j0];
        float2 k1 = *(const float2*)&Kmat[(size_t)i1 * ZDIM + j0];
        float2 k2 = *(const float2*)&Kmat[(size_t)i2 * ZDIM + j0];
        float2 k3 = *(const float2*)&Kmat[(size_t)i3 * ZDIM + j0];
        float2 a0 = make_float2(bj.x + k0.x, bj.y + k0.y);
        float2 a1 = make_float2(bj.x + k1.x, bj.y + k1.y);
        float2 a2 = make_float2(bj.x + k2.x, bj.y + k2.y);
        float2 a3 = make_float2(bj.x + k3.x, bj.y + k3.y);
        recLoop(a0, a1, a2, a3);
        *(float2*)&sZ[0][j0] = a0; *(float2*)&sZ[1][j0] = a1;
        *(float2*)&sZ[2][j0] = a2; *(float2*)&sZ[3][j0] = a3;
        __syncthreads();
        phaseB();
        __syncthreads();
    }
    softmaxStore(0);
    for (int s = 1; s < OSTEPS; ++s) {
        float2 bj = *(const float2*)&sBias[j0];
        float2 a0 = make_float2(bj.x, bj.y), a1 = a0, a2 = a0, a3 = a0;
        #pragma unroll 8
        for (int i = 0; i < NFEAT; ++i) {
            float2 w  = *(const float2*)&Kmat[(size_t)i * ZDIM + j0];
            float4 p4 = *(const float4*)&sPT[i][0];
            a0.x = fmaf(p4.x, w.x, a0.x); a0.y = fmaf(p4.x, w.y, a0.y);
            a1.x = fmaf(p4.y, w.x, a1.x); a1.y = fmaf(p4.y, w.y, a1.y);
            a2.x = fmaf(p4.z, w.x, a2.x); a2.y = fmaf(p4.z, w.y, a2.y);
            a3.x = fmaf(p4.w, w.x, a3.x); a3.y = fmaf(p4.w, w.y, a3.y);
        }
        recLoop(a0, a1, a2, a3);
        *(float2*)&sZ[0][j0] = a0; *(float2*)&sZ[1][j0] = a1;
        *(float2*)&sZ[2][j0] = a2; *(float2*)&sZ[3][j0] = a3;
        __syncthreads();
        phaseB();
        __syncthreads();
        softmaxStore(s);
    }
}

extern "C" void kernel_launch(void* const* d_in, const int* in_sizes, int n_in,
                              void* d_out, int out_size, void* d_ws, size_t ws_size,
                              hipStream_t stream) {
    const float* inputs = (const float*)d_in[0];
    const float* kernel = (const float*)d_in[1];
    const float* rec    = (const float*)d_in[2];
    const float* bias   = (const float*)d_in[3];
    const float* dw     = (const float*)d_in[4];
    const float* db     = (const float*)d_in[5];
    float* out = (float*)d_out;

    float* tb  = (float*)d_ws;       // 64 floats
    float* muv = tb + 64;            // 512
    float* sgv = muv + BATCH;        // 512  -> ends at byte 4352

    const size_t recpg_off = 4352;
    const size_t kb_off    = recpg_off + 131072u * 4u;   // 528640
    const size_t need      = kb_off + 32768u * 4u;       // 659712

    k_tbase<<<1, 32, 0, stream>>>(tb);
    k_musig<<<BATCH, 1024, 0, stream>>>(inputs, out, muv, sgv);

    if (ws_size >= need) {
        unsigned int* RecPG = (unsigned int*)((char*)d_ws + recpg_off);
        float*        KB    = (float*)((char*)d_ws + kb_off);
        k_packR<<<512, 256, 0, stream>>>(rec, RecPG);
        k_packK<<<128, 256, 0, stream>>>(kernel, bias, KB);
        k_lstm3<<<BATCH / 2, 512, 0, stream>>>(inputs, RecPG, KB, dw, db,
                                               tb, muv, sgv, out);
    } else {
        k_lstm<<<BATCH / BT, NTHR, 0, stream>>>(inputs, kernel, rec, bias, dw, db,
                                                tb, muv, sgv, out);
    }
}